// Round 1
// baseline (459.732 us; speedup 1.0000x reference)
//
#include <hip/hip_runtime.h>

#define IN_F   2048
#define OUT_F  2048
#define GDIM   8
#define BATCH  8192
#define KDIM   4096   // concat K = 2*2048
#define GRID_TOTAL_INV (1.0f / 33554432.0f)  // 1/(2048*2048*8)

typedef __bf16 bf16x8 __attribute__((ext_vector_type(8)));
typedef float  f32x4  __attribute__((ext_vector_type(4)));
typedef unsigned short u16x8 __attribute__((ext_vector_type(8)));

__device__ __forceinline__ unsigned short f2bf(float f) {
  union { float f; unsigned int u; } v; v.f = f;
  unsigned int r = v.u + 0x7fffu + ((v.u >> 16) & 1u);  // RNE
  return (unsigned short)(r >> 16);
}

__device__ __forceinline__ void gload_lds16(const void* g, void* l) {
  __builtin_amdgcn_global_load_lds(
      (const __attribute__((address_space(1))) void*)g,
      (__attribute__((address_space(3))) void*)l, 16, 0, 0);
}

// ---------------- prep 1: base_weight (OUT,IN) f32 -> Bt[o][k<2048] bf16 ----
__global__ __launch_bounds__(256) void prep_bw(const float* __restrict__ bw,
                                               unsigned short* __restrict__ Bt,
                                               float* __restrict__ sum_ptr) {
  if (blockIdx.x == 0 && threadIdx.x == 0) *sum_ptr = 0.0f;  // zero mean-acc
  size_t i8 = ((size_t)blockIdx.x * 256 + threadIdx.x) * 8;
  const float4* p = reinterpret_cast<const float4*>(bw + i8);
  float4 a = p[0], b = p[1];
  u16x8 v;
  v[0] = f2bf(a.x); v[1] = f2bf(a.y); v[2] = f2bf(a.z); v[3] = f2bf(a.w);
  v[4] = f2bf(b.x); v[5] = f2bf(b.y); v[6] = f2bf(b.z); v[7] = f2bf(b.w);
  size_t o = i8 >> 11;       // row (out)
  size_t k = i8 & 2047;      // col (in)
  *reinterpret_cast<u16x8*>(Bt + o * KDIM + k) = v;
}

// ---------------- prep 2: grid (IN,OUT,8) f32 -> Bt[o][2048+i] = sum_g, + mean
__global__ __launch_bounds__(256) void prep_grid(const float* __restrict__ grid,
                                                 unsigned short* __restrict__ Bt,
                                                 float* __restrict__ sum_ptr) {
  __shared__ float tile[32][33];
  __shared__ float wsum[4];
  int bi = blockIdx.x >> 6;   // i-tile (64 tiles of 32)
  int bo = blockIdx.x & 63;   // o-tile
  int i0 = bi << 5, o0 = bo << 5;
  int t = threadIdx.x;
  float local = 0.f;
#pragma unroll
  for (int p = 0; p < 4; ++p) {
    int li = t + 256 * p;
    int il = li >> 5, ol = li & 31;
    const float4* g4 = reinterpret_cast<const float4*>(
        grid + ((size_t)(i0 + il) * OUT_F + (size_t)(o0 + ol)) * GDIM);
    float4 a = g4[0], b = g4[1];
    float s = ((a.x + a.y) + (a.z + a.w)) + ((b.x + b.y) + (b.z + b.w));
    tile[il][ol] = s;
    local += s;
  }
#pragma unroll
  for (int off = 32; off >= 1; off >>= 1) local += __shfl_down(local, off, 64);
  int lane = t & 63, w = t >> 6;
  if (lane == 0) wsum[w] = local;
  __syncthreads();
#pragma unroll
  for (int p = 0; p < 4; ++p) {
    int li = t + 256 * p;
    int ol = li >> 5, il = li & 31;   // transposed: consecutive t -> consecutive i
    Bt[(size_t)(o0 + ol) * KDIM + IN_F + (i0 + il)] = f2bf(tile[il][ol]);
  }
  if (t == 0) atomicAdd(sum_ptr, (wsum[0] + wsum[1]) + (wsum[2] + wsum[3]));
}

// ---------------- prep 3: A = [bf16(x) | bf16(exp(-(x-m)^2))] ----------------
__global__ __launch_bounds__(256) void prep_A(const float* __restrict__ x,
                                              const float* __restrict__ sum_ptr,
                                              unsigned short* __restrict__ Abuf) {
  float m = *sum_ptr * GRID_TOTAL_INV;
  size_t i8 = ((size_t)blockIdx.x * 256 + threadIdx.x) * 8;
  const float4* p = reinterpret_cast<const float4*>(x + i8);
  float4 a = p[0], b = p[1];
  float xs[8] = {a.x, a.y, a.z, a.w, b.x, b.y, b.z, b.w};
  u16x8 xv, bv;
#pragma unroll
  for (int j = 0; j < 8; ++j) {
    xv[j] = f2bf(xs[j]);
    float d = xs[j] - m;
    bv[j] = f2bf(__expf(-d * d));
  }
  size_t bi = i8 >> 11;
  size_t k  = i8 & 2047;
  *reinterpret_cast<u16x8*>(Abuf + bi * KDIM + k) = xv;
  *reinterpret_cast<u16x8*>(Abuf + bi * KDIM + IN_F + k) = bv;
}

// ---------------- GEMM: C(8192x2048) = A(8192x4096) * Bt(2048x4096)^T --------
// 128x128 tile, BK=64, 4 waves (2x2), each wave 64x64 via 4x4 frags of 16x16x32.
// XOR chunk-swizzle (chunk ^ (row&7)) applied on the global SOURCE during
// global_load_lds staging (LDS dest linear) and identically on ds_read.
__global__ __launch_bounds__(256) void gemm_kernel(
    const unsigned short* __restrict__ A,
    const unsigned short* __restrict__ B,
    float* __restrict__ C) {
  __shared__ unsigned short As[128 * 64];  // 16 KB
  __shared__ unsigned short Bs[128 * 64];  // 16 KB
  int bm = blockIdx.x & 63;   // 64 M-tiles
  int bn = blockIdx.x >> 6;   // 16 N-tiles
  int t = threadIdx.x;
  int lane = t & 63;
  int wid  = t >> 6;
  int wm = wid >> 1, wn = wid & 1;

  const f32x4 fzero = {0.f, 0.f, 0.f, 0.f};
  f32x4 acc[4][4];
#pragma unroll
  for (int m = 0; m < 4; ++m)
#pragma unroll
    for (int n = 0; n < 4; ++n) acc[m][n] = fzero;

  const size_t a_row0 = (size_t)bm * 128;
  const size_t b_row0 = (size_t)bn * 128;

  // staging geometry (per thread, loop-invariant)
  const int pbase = wid * 1024 + lane * 16;

  for (int step = 0; step < 64; ++step) {
    const int k0 = step * 64;
#pragma unroll
    for (int issue = 0; issue < 4; ++issue) {
      int p  = issue * 4096 + pbase;
      int r  = p >> 7;                       // tile row 0..127
      int cg = ((p >> 4) & 7) ^ (r & 7);     // swizzled source chunk
      gload_lds16(A + (a_row0 + r) * KDIM + k0 + cg * 8,
                  (char*)As + issue * 4096 + wid * 1024);
      gload_lds16(B + (b_row0 + r) * KDIM + k0 + cg * 8,
                  (char*)Bs + issue * 4096 + wid * 1024);
    }
    __syncthreads();  // drains vmcnt(0): gload_lds complete, tiles visible
#pragma unroll
    for (int kk = 0; kk < 2; ++kk) {
      bf16x8 af[4], bfr[4];
#pragma unroll
      for (int m = 0; m < 4; ++m) {
        int r = wm * 64 + m * 16 + (lane & 15);
        int c = (kk * 4 + (lane >> 4)) ^ (r & 7);
        af[m] = *reinterpret_cast<const bf16x8*>((const char*)As + r * 128 + c * 16);
      }
#pragma unroll
      for (int n = 0; n < 4; ++n) {
        int r = wn * 64 + n * 16 + (lane & 15);
        int c = (kk * 4 + (lane >> 4)) ^ (r & 7);
        bfr[n] = *reinterpret_cast<const bf16x8*>((const char*)Bs + r * 128 + c * 16);
      }
#pragma unroll
      for (int m = 0; m < 4; ++m)
#pragma unroll
        for (int n = 0; n < 4; ++n)
          acc[m][n] = __builtin_amdgcn_mfma_f32_16x16x32_bf16(
              af[m], bfr[n], acc[m][n], 0, 0, 0);
    }
    __syncthreads();  // protect LDS before next stage
  }

  // epilogue: C/D layout col=lane&15, row=(lane>>4)*4+reg  [m89/m91 verified]
  int rg = lane >> 4, cc = lane & 15;
  size_t crow0 = (size_t)bm * 128 + wm * 64;
  size_t ccol0 = (size_t)bn * 128 + wn * 64;
#pragma unroll
  for (int m = 0; m < 4; ++m)
#pragma unroll
    for (int n = 0; n < 4; ++n)
#pragma unroll
      for (int rr = 0; rr < 4; ++rr) {
        size_t row = crow0 + (size_t)m * 16 + rg * 4 + rr;
        size_t col = ccol0 + (size_t)n * 16 + cc;
        C[row * OUT_F + col] = acc[m][n][rr];
      }
}

extern "C" void kernel_launch(void* const* d_in, const int* in_sizes, int n_in,
                              void* d_out, int out_size, void* d_ws, size_t ws_size,
                              hipStream_t stream) {
  const float* x    = (const float*)d_in[0];
  const float* bw   = (const float*)d_in[1];
  const float* grid = (const float*)d_in[2];
  float* out = (float*)d_out;

  // workspace layout: A (8192x4096 bf16, 64MB) | Bt (2048x4096 bf16, 16MB) | sum (4B)
  unsigned short* Abuf = (unsigned short*)d_ws;
  unsigned short* Bt   = Abuf + (size_t)BATCH * KDIM;
  float* sum_ptr = (float*)(Bt + (size_t)OUT_F * KDIM);

  prep_bw  <<<(OUT_F * IN_F / 8) / 256, 256, 0, stream>>>(bw, Bt, sum_ptr);
  prep_grid<<<64 * 64,                  256, 0, stream>>>(grid, Bt, sum_ptr);
  prep_A   <<<(BATCH * IN_F / 8) / 256, 256, 0, stream>>>(x, sum_ptr, Abuf);
  gemm_kernel<<<64 * 16, 256, 0, stream>>>(Abuf, Bt, out);
}

// Round 2
// 416.632 us; speedup vs baseline: 1.1034x; 1.1034x over previous
//
#include <hip/hip_runtime.h>

#define IN_F   2048
#define OUT_F  2048
#define GDIM   8
#define BATCH  8192
#define KDIM   4096   // concat K = 2*2048
#define GRID_TOTAL_INV (1.0f / 33554432.0f)  // 1/(2048*2048*8)

#define BK     32
#define NT     (KDIM / BK)   // 128 K-tiles
#define SLOT   32768         // ring slot: A 16K + B 16K
#define ATILE  16384

typedef __bf16 bf16x8 __attribute__((ext_vector_type(8)));
typedef float  f32x4  __attribute__((ext_vector_type(4)));
typedef unsigned short u16x8 __attribute__((ext_vector_type(8)));

__device__ __forceinline__ unsigned short f2bf(float f) {
  union { float f; unsigned int u; } v; v.f = f;
  unsigned int r = v.u + 0x7fffu + ((v.u >> 16) & 1u);  // RNE
  return (unsigned short)(r >> 16);
}

__device__ __forceinline__ void gload_lds16(const void* g, void* l) {
  __builtin_amdgcn_global_load_lds(
      (const __attribute__((address_space(1))) void*)g,
      (__attribute__((address_space(3))) void*)l, 16, 0, 0);
}

template<int VM>
__device__ __forceinline__ void wait_vm() {
  if constexpr (VM == 12)     asm volatile("s_waitcnt vmcnt(12)" ::: "memory");
  else if constexpr (VM == 8) asm volatile("s_waitcnt vmcnt(8)"  ::: "memory");
  else if constexpr (VM == 4) asm volatile("s_waitcnt vmcnt(4)"  ::: "memory");
  else                        asm volatile("s_waitcnt vmcnt(0)"  ::: "memory");
}

// ---------------- prep 1: base_weight (OUT,IN) f32 -> Bt[o][k<2048] bf16 ----
__global__ __launch_bounds__(256) void prep_bw(const float* __restrict__ bw,
                                               unsigned short* __restrict__ Bt,
                                               float* __restrict__ sum_ptr) {
  if (blockIdx.x == 0 && threadIdx.x == 0) *sum_ptr = 0.0f;  // zero mean-acc
  size_t i8 = ((size_t)blockIdx.x * 256 + threadIdx.x) * 8;
  const float4* p = reinterpret_cast<const float4*>(bw + i8);
  float4 a = p[0], b = p[1];
  u16x8 v;
  v[0] = f2bf(a.x); v[1] = f2bf(a.y); v[2] = f2bf(a.z); v[3] = f2bf(a.w);
  v[4] = f2bf(b.x); v[5] = f2bf(b.y); v[6] = f2bf(b.z); v[7] = f2bf(b.w);
  size_t o = i8 >> 11;       // row (out)
  size_t k = i8 & 2047;      // col (in)
  *reinterpret_cast<u16x8*>(Bt + o * KDIM + k) = v;
}

// ---------------- prep 2: grid (IN,OUT,8) f32 -> Bt[o][2048+i] = sum_g, + mean
__global__ __launch_bounds__(256) void prep_grid(const float* __restrict__ grid,
                                                 unsigned short* __restrict__ Bt,
                                                 float* __restrict__ sum_ptr) {
  __shared__ float tile[32][33];
  __shared__ float wsum[4];
  int bi = blockIdx.x >> 6;   // i-tile (64 tiles of 32)
  int bo = blockIdx.x & 63;   // o-tile
  int i0 = bi << 5, o0 = bo << 5;
  int t = threadIdx.x;
  float local = 0.f;
#pragma unroll
  for (int p = 0; p < 4; ++p) {
    int li = t + 256 * p;
    int il = li >> 5, ol = li & 31;
    const float4* g4 = reinterpret_cast<const float4*>(
        grid + ((size_t)(i0 + il) * OUT_F + (size_t)(o0 + ol)) * GDIM);
    float4 a = g4[0], b = g4[1];
    float s = ((a.x + a.y) + (a.z + a.w)) + ((b.x + b.y) + (b.z + b.w));
    tile[il][ol] = s;
    local += s;
  }
#pragma unroll
  for (int off = 32; off >= 1; off >>= 1) local += __shfl_down(local, off, 64);
  int lane = t & 63, w = t >> 6;
  if (lane == 0) wsum[w] = local;
  __syncthreads();
#pragma unroll
  for (int p = 0; p < 4; ++p) {
    int li = t + 256 * p;
    int ol = li >> 5, il = li & 31;   // transposed: consecutive t -> consecutive i
    Bt[(size_t)(o0 + ol) * KDIM + IN_F + (i0 + il)] = f2bf(tile[il][ol]);
  }
  if (t == 0) atomicAdd(sum_ptr, (wsum[0] + wsum[1]) + (wsum[2] + wsum[3]));
}

// ---------------- prep 3: A = [bf16(x) | bf16(exp(-(x-m)^2))] ----------------
__global__ __launch_bounds__(256) void prep_A(const float* __restrict__ x,
                                              const float* __restrict__ sum_ptr,
                                              unsigned short* __restrict__ Abuf) {
  float m = *sum_ptr * GRID_TOTAL_INV;
  size_t i8 = ((size_t)blockIdx.x * 256 + threadIdx.x) * 8;
  const float4* p = reinterpret_cast<const float4*>(x + i8);
  float4 a = p[0], b = p[1];
  float xs[8] = {a.x, a.y, a.z, a.w, b.x, b.y, b.z, b.w};
  u16x8 xv, bv;
#pragma unroll
  for (int j = 0; j < 8; ++j) {
    xv[j] = f2bf(xs[j]);
    float d = xs[j] - m;
    bv[j] = f2bf(__expf(-d * d));
  }
  size_t bi = i8 >> 11;
  size_t k  = i8 & 2047;
  *reinterpret_cast<u16x8*>(Abuf + bi * KDIM + k) = xv;
  *reinterpret_cast<u16x8*>(Abuf + bi * KDIM + IN_F + k) = bv;
}

// ---------------- GEMM: C(8192x2048) = A(8192x4096) * Bt(2048x4096)^T --------
// 256x256 tile, BK=32, 8 waves (2Mx4N), per-wave 128x64 via 8x4 frags 16x16x32.
// 4-slot LDS ring (128 KiB), prefetch depth 3, counted vmcnt(12) (T3+T4),
// raw s_barrier (no __syncthreads vmcnt(0) drain), setprio around MFMA (T5).
// BK=32 + linear [256][32] LDS => each wave's frag region is a contiguous
// 1024B block => conflict-free ds_read_b128 without swizzle; and
// global_load_lds dest stays linear (rule 21 satisfied trivially).
__global__ __launch_bounds__(512, 2) void gemm_kernel(
    const unsigned short* __restrict__ A,
    const unsigned short* __restrict__ B,
    float* __restrict__ C) {
  __shared__ __align__(16) char lds[4 * SLOT];  // 128 KiB
  const int t    = threadIdx.x;
  const int lane = t & 63;
  const int wid  = t >> 6;        // 0..7
  const int wm   = wid >> 2;      // 0..1
  const int wn   = wid & 3;       // 0..3
  // XCD-clustered mapping: xcd = bx&7 gets bm in [xcd*4, xcd*4+4) x all 8 bn.
  const int bx = blockIdx.x;
  const int bm = ((bx & 7) << 2) | ((bx >> 3) & 3);  // 0..31
  const int bn = bx >> 5;                            // 0..7

  f32x4 acc[8][4] = {};

  // staging geometry: thread t covers dest row (t>>2)+j*128, col bytes (t&3)*16
  const unsigned short* aSrc = A + ((size_t)(bm * 256 + (t >> 2)) * KDIM) + (t & 3) * 8;
  const unsigned short* bSrc = B + ((size_t)(bn * 256 + (t >> 2)) * KDIM) + (t & 3) * 8;
  const int dstOff = t * 16;

  // per-wave LDS read offsets (bytes): row stride 64B, frag chunk (lane>>4)*16
  const int aRd = (wm * 128 + (lane & 15)) * 64 + (lane >> 4) * 16;
  const int bRd = (wn * 64  + (lane & 15)) * 64 + (lane >> 4) * 16;

  auto STAGE = [&](int tile) {
    const int slot = (tile & 3) * SLOT;
    const unsigned short* a = aSrc + tile * BK;
    const unsigned short* b = bSrc + tile * BK;
    gload_lds16(a,                        lds + slot + dstOff);
    gload_lds16(a + 128 * KDIM,           lds + slot + 8192 + dstOff);
    gload_lds16(b,                        lds + slot + ATILE + dstOff);
    gload_lds16(b + 128 * KDIM,           lds + slot + ATILE + 8192 + dstOff);
  };

  auto BODY = [&](int slotbase) {
    __builtin_amdgcn_sched_barrier(0);
    const char* sa = lds + slotbase + aRd;
    const char* sb = lds + slotbase + ATILE + bRd;
    bf16x8 af[8], bf[4];
#pragma unroll
    for (int m = 0; m < 8; ++m)
      af[m] = *reinterpret_cast<const bf16x8*>(sa + m * 1024);
#pragma unroll
    for (int n = 0; n < 4; ++n)
      bf[n] = *reinterpret_cast<const bf16x8*>(sb + n * 1024);
    asm volatile("s_waitcnt lgkmcnt(0)" ::: "memory");
    __builtin_amdgcn_sched_barrier(0);   // rule 18: MFMA must not hoist above
    __builtin_amdgcn_s_barrier();        // barrier2: all waves done reading slot
    __builtin_amdgcn_s_setprio(1);
#pragma unroll
    for (int m = 0; m < 8; ++m)
#pragma unroll
      for (int n = 0; n < 4; ++n)
        acc[m][n] = __builtin_amdgcn_mfma_f32_16x16x32_bf16(af[m], bf[n], acc[m][n], 0, 0, 0);
    __builtin_amdgcn_s_setprio(0);
  };

  // prologue: 3 tiles in flight
  STAGE(0); STAGE(1); STAGE(2);

  for (int kt = 0; kt < NT - 3; ++kt) {
    STAGE(kt + 3);                       // into slot (kt+3)&3 = (kt-1)&3, freed by barrier2(kt-1)
    wait_vm<12>();                       // own tile-kt loads landed (3 tiles newer in flight)
    __builtin_amdgcn_s_barrier();        // barrier1: tile kt visible to all
    BODY((kt & 3) * SLOT);
  }
  wait_vm<8>(); __builtin_amdgcn_s_barrier(); BODY(((NT - 3) & 3) * SLOT);
  wait_vm<4>(); __builtin_amdgcn_s_barrier(); BODY(((NT - 2) & 3) * SLOT);
  wait_vm<0>(); __builtin_amdgcn_s_barrier(); BODY(((NT - 1) & 3) * SLOT);

  // epilogue: C/D layout col=lane&15, row=(lane>>4)*4+reg  [m89/m91 verified]
  const int rg = lane >> 4, cc = lane & 15;
  const size_t crow0 = (size_t)bm * 256 + wm * 128;
  const size_t ccol0 = (size_t)bn * 256 + wn * 64;
#pragma unroll
  for (int m = 0; m < 8; ++m)
#pragma unroll
    for (int n = 0; n < 4; ++n)
#pragma unroll
      for (int rr = 0; rr < 4; ++rr) {
        size_t row = crow0 + (size_t)m * 16 + rg * 4 + rr;
        size_t col = ccol0 + (size_t)n * 16 + cc;
        C[row * OUT_F + col] = acc[m][n][rr];
      }
}

extern "C" void kernel_launch(void* const* d_in, const int* in_sizes, int n_in,
                              void* d_out, int out_size, void* d_ws, size_t ws_size,
                              hipStream_t stream) {
  const float* x    = (const float*)d_in[0];
  const float* bw   = (const float*)d_in[1];
  const float* grid = (const float*)d_in[2];
  float* out = (float*)d_out;

  // workspace: A (8192x4096 bf16, 64MB) | Bt (2048x4096 bf16, 16MB) | sum (4B)
  unsigned short* Abuf = (unsigned short*)d_ws;
  unsigned short* Bt   = Abuf + (size_t)BATCH * KDIM;
  float* sum_ptr = (float*)(Bt + (size_t)OUT_F * KDIM);

  prep_bw  <<<(OUT_F * IN_F / 8) / 256, 256, 0, stream>>>(bw, Bt, sum_ptr);
  prep_grid<<<64 * 64,                  256, 0, stream>>>(grid, Bt, sum_ptr);
  prep_A   <<<(BATCH * IN_F / 8) / 256, 256, 0, stream>>>(x, sum_ptr, Abuf);
  gemm_kernel<<<256, 512, 0, stream>>>(Abuf, Bt, out);
}

// Round 3
// 416.516 us; speedup vs baseline: 1.1038x; 1.0003x over previous
//
#include <hip/hip_runtime.h>

#define IN_F   2048
#define OUT_F  2048
#define GDIM   8
#define BATCH  8192
#define KDIM   4096   // concat K = 2*2048
#define GRID_TOTAL_INV (1.0f / 33554432.0f)  // 1/(2048*2048*8)

#define BK     32
#define NT     (KDIM / BK)   // 128 K-tiles
#define SLOT   32768         // ring slot: A 16K + B 16K
#define ATILE  16384

typedef __bf16 bf16x8 __attribute__((ext_vector_type(8)));
typedef float  f32x4  __attribute__((ext_vector_type(4)));
typedef unsigned short u16x8 __attribute__((ext_vector_type(8)));

__device__ __forceinline__ unsigned short f2bf(float f) {
  union { float f; unsigned int u; } v; v.f = f;
  unsigned int r = v.u + 0x7fffu + ((v.u >> 16) & 1u);  // RNE
  return (unsigned short)(r >> 16);
}

__device__ __forceinline__ void gload_lds16(const void* g, void* l) {
  __builtin_amdgcn_global_load_lds(
      (const __attribute__((address_space(1))) void*)g,
      (__attribute__((address_space(3))) void*)l, 16, 0, 0);
}

template<int VM>
__device__ __forceinline__ void wait_vm() {
  if constexpr (VM == 12)     asm volatile("s_waitcnt vmcnt(12)" ::: "memory");
  else if constexpr (VM == 8) asm volatile("s_waitcnt vmcnt(8)"  ::: "memory");
  else if constexpr (VM == 4) asm volatile("s_waitcnt vmcnt(4)"  ::: "memory");
  else                        asm volatile("s_waitcnt vmcnt(0)"  ::: "memory");
}

// ---------------- prep 1: base_weight (OUT,IN) f32 -> Bt[o][k<2048] bf16 ----
__global__ __launch_bounds__(256) void prep_bw(const float* __restrict__ bw,
                                               unsigned short* __restrict__ Bt,
                                               float* __restrict__ sum_ptr) {
  if (blockIdx.x == 0 && threadIdx.x == 0) *sum_ptr = 0.0f;  // zero mean-acc
  size_t i8 = ((size_t)blockIdx.x * 256 + threadIdx.x) * 8;
  const float4* p = reinterpret_cast<const float4*>(bw + i8);
  float4 a = p[0], b = p[1];
  u16x8 v;
  v[0] = f2bf(a.x); v[1] = f2bf(a.y); v[2] = f2bf(a.z); v[3] = f2bf(a.w);
  v[4] = f2bf(b.x); v[5] = f2bf(b.y); v[6] = f2bf(b.z); v[7] = f2bf(b.w);
  size_t o = i8 >> 11;       // row (out)
  size_t k = i8 & 2047;      // col (in)
  *reinterpret_cast<u16x8*>(Bt + o * KDIM + k) = v;
}

// ---------------- prep 2: grid (IN,OUT,8) f32 -> Bt[o][2048+i] = sum_g, + mean
__global__ __launch_bounds__(256) void prep_grid(const float* __restrict__ grid,
                                                 unsigned short* __restrict__ Bt,
                                                 float* __restrict__ sum_ptr) {
  __shared__ float tile[32][33];
  __shared__ float wsum[4];
  int bi = blockIdx.x >> 6;   // i-tile (64 tiles of 32)
  int bo = blockIdx.x & 63;   // o-tile
  int i0 = bi << 5, o0 = bo << 5;
  int t = threadIdx.x;
  float local = 0.f;
#pragma unroll
  for (int p = 0; p < 4; ++p) {
    int li = t + 256 * p;
    int il = li >> 5, ol = li & 31;
    const float4* g4 = reinterpret_cast<const float4*>(
        grid + ((size_t)(i0 + il) * OUT_F + (size_t)(o0 + ol)) * GDIM);
    float4 a = g4[0], b = g4[1];
    float s = ((a.x + a.y) + (a.z + a.w)) + ((b.x + b.y) + (b.z + b.w));
    tile[il][ol] = s;
    local += s;
  }
#pragma unroll
  for (int off = 32; off >= 1; off >>= 1) local += __shfl_down(local, off, 64);
  int lane = t & 63, w = t >> 6;
  if (lane == 0) wsum[w] = local;
  __syncthreads();
#pragma unroll
  for (int p = 0; p < 4; ++p) {
    int li = t + 256 * p;
    int ol = li >> 5, il = li & 31;   // transposed: consecutive t -> consecutive i
    Bt[(size_t)(o0 + ol) * KDIM + IN_F + (i0 + il)] = f2bf(tile[il][ol]);
  }
  if (t == 0) atomicAdd(sum_ptr, (wsum[0] + wsum[1]) + (wsum[2] + wsum[3]));
}

// ---------------- prep 3: A = [bf16(x) | bf16(exp(-(x-m)^2))] ----------------
__global__ __launch_bounds__(256) void prep_A(const float* __restrict__ x,
                                              const float* __restrict__ sum_ptr,
                                              unsigned short* __restrict__ Abuf) {
  float m = *sum_ptr * GRID_TOTAL_INV;
  size_t i8 = ((size_t)blockIdx.x * 256 + threadIdx.x) * 8;
  const float4* p = reinterpret_cast<const float4*>(x + i8);
  float4 a = p[0], b = p[1];
  float xs[8] = {a.x, a.y, a.z, a.w, b.x, b.y, b.z, b.w};
  u16x8 xv, bv;
#pragma unroll
  for (int j = 0; j < 8; ++j) {
    xv[j] = f2bf(xs[j]);
    float d = xs[j] - m;
    bv[j] = f2bf(__expf(-d * d));
  }
  size_t bi = i8 >> 11;
  size_t k  = i8 & 2047;
  *reinterpret_cast<u16x8*>(Abuf + bi * KDIM + k) = xv;
  *reinterpret_cast<u16x8*>(Abuf + bi * KDIM + IN_F + k) = bv;
}

// ---------------- GEMM: C(8192x2048) = A(8192x4096) * Bt(2048x4096)^T --------
// 256x256 tile, BK=32, 8 waves (2Mx4N), per-wave 128x64 via 8x4 frags 16x16x32.
// 4-slot LDS ring (128 KiB), prefetch depth 3, counted vmcnt(12) (T3+T4),
// raw s_barrier, setprio around MFMA (T5).
// LDS chunk-swizzle (rule 21, both-sides): 16B-chunk c stored at c^((row>>2)&3)
// via pre-swizzled GLOBAL source (LDS dest linear for global_load_lds);
// ds_read applies the same XOR. Bank-slot = (row&1)*4 + swz-chunk: each of 8
// slots hit by exactly 2 of 16 lanes -> 2-way aliasing = free (m136).
__global__ __launch_bounds__(512, 2) void gemm_kernel(
    const unsigned short* __restrict__ A,
    const unsigned short* __restrict__ B,
    float* __restrict__ C) {
  __shared__ __align__(16) char lds[4 * SLOT];  // 128 KiB
  const int t    = threadIdx.x;
  const int lane = t & 63;
  const int wid  = t >> 6;        // 0..7
  const int wm   = wid >> 2;      // 0..1
  const int wn   = wid & 3;       // 0..3
  // XCD-clustered mapping: xcd = bx&7 gets bm in [xcd*4, xcd*4+4) x all 8 bn.
  const int bx = blockIdx.x;
  const int bm = ((bx & 7) << 2) | ((bx >> 3) & 3);  // 0..31
  const int bn = bx >> 5;                            // 0..7

  f32x4 acc[8][4] = {};

  // staging: thread t fills dest rows (t>>2) and 128+(t>>2), chunk (t&3).
  // Source k-chunk pre-swizzled: cs = (t&3) ^ ((row>>2)&3); (row>>2)&3 is
  // (t>>4)&3 for both halves (128>>2 = 32 ≡ 0 mod 4).
  const int cs = (t & 3) ^ ((t >> 4) & 3);
  const unsigned short* aSrc = A + ((size_t)(bm * 256 + (t >> 2)) * KDIM) + cs * 8;
  const unsigned short* bSrc = B + ((size_t)(bn * 256 + (t >> 2)) * KDIM) + cs * 8;
  const int dstOff = t * 16;

  // per-wave LDS read offsets (bytes): row stride 64B; global k-chunk (lane>>4)
  // lives at LDS chunk (lane>>4) ^ ((row>>2)&3); ((row>>2)&3) == ((lane>>2)&3)
  // since row = base16 + (lane&15) with base16 % 64 == 0 here.
  const int swz = (lane >> 2) & 3;
  const int aRd = (wm * 128 + (lane & 15)) * 64 + (((lane >> 4) ^ swz) * 16);
  const int bRd = (wn * 64  + (lane & 15)) * 64 + (((lane >> 4) ^ swz) * 16);

  auto STAGE = [&](int tile) {
    const int slot = (tile & 3) * SLOT;
    const unsigned short* a = aSrc + tile * BK;
    const unsigned short* b = bSrc + tile * BK;
    gload_lds16(a,                        lds + slot + dstOff);
    gload_lds16(a + 128 * KDIM,           lds + slot + 8192 + dstOff);
    gload_lds16(b,                        lds + slot + ATILE + dstOff);
    gload_lds16(b + 128 * KDIM,           lds + slot + ATILE + 8192 + dstOff);
  };

  auto BODY = [&](int slotbase) {
    __builtin_amdgcn_sched_barrier(0);
    const char* sa = lds + slotbase + aRd;
    const char* sb = lds + slotbase + ATILE + bRd;
    bf16x8 af[8], bf[4];
#pragma unroll
    for (int m = 0; m < 8; ++m)
      af[m] = *reinterpret_cast<const bf16x8*>(sa + m * 1024);
#pragma unroll
    for (int n = 0; n < 4; ++n)
      bf[n] = *reinterpret_cast<const bf16x8*>(sb + n * 1024);
    asm volatile("s_waitcnt lgkmcnt(0)" ::: "memory");
    __builtin_amdgcn_sched_barrier(0);   // rule 18: MFMA must not hoist above
    __builtin_amdgcn_s_barrier();        // barrier2: all waves done reading slot
    __builtin_amdgcn_s_setprio(1);
#pragma unroll
    for (int m = 0; m < 8; ++m)
#pragma unroll
      for (int n = 0; n < 4; ++n)
        acc[m][n] = __builtin_amdgcn_mfma_f32_16x16x32_bf16(af[m], bf[n], acc[m][n], 0, 0, 0);
    __builtin_amdgcn_s_setprio(0);
  };

  // prologue: 3 tiles in flight
  STAGE(0); STAGE(1); STAGE(2);

  for (int kt = 0; kt < NT - 3; ++kt) {
    STAGE(kt + 3);                       // into slot freed by barrier2(kt-1)
    wait_vm<12>();                       // own tile-kt loads landed
    __builtin_amdgcn_s_barrier();        // barrier1: tile kt visible to all
    BODY((kt & 3) * SLOT);
  }
  wait_vm<8>(); __builtin_amdgcn_s_barrier(); BODY(((NT - 3) & 3) * SLOT);
  wait_vm<4>(); __builtin_amdgcn_s_barrier(); BODY(((NT - 2) & 3) * SLOT);
  wait_vm<0>(); __builtin_amdgcn_s_barrier(); BODY(((NT - 1) & 3) * SLOT);

  // epilogue: C/D layout col=lane&15, row=(lane>>4)*4+reg  [m89/m91 verified]
  const int rg = lane >> 4, cc = lane & 15;
  const size_t crow0 = (size_t)bm * 256 + wm * 128;
  const size_t ccol0 = (size_t)bn * 256 + wn * 64;
#pragma unroll
  for (int m = 0; m < 8; ++m)
#pragma unroll
    for (int n = 0; n < 4; ++n)
#pragma unroll
      for (int rr = 0; rr < 4; ++rr) {
        size_t row = crow0 + (size_t)m * 16 + rg * 4 + rr;
        size_t col = ccol0 + (size_t)n * 16 + cc;
        C[row * OUT_F + col] = acc[m][n][rr];
      }
}

extern "C" void kernel_launch(void* const* d_in, const int* in_sizes, int n_in,
                              void* d_out, int out_size, void* d_ws, size_t ws_size,
                              hipStream_t stream) {
  const float* x    = (const float*)d_in[0];
  const float* bw   = (const float*)d_in[1];
  const float* grid = (const float*)d_in[2];
  float* out = (float*)d_out;

  // workspace: A (8192x4096 bf16, 64MB) | Bt (2048x4096 bf16, 16MB) | sum (4B)
  unsigned short* Abuf = (unsigned short*)d_ws;
  unsigned short* Bt   = Abuf + (size_t)BATCH * KDIM;
  float* sum_ptr = (float*)(Bt + (size_t)OUT_F * KDIM);

  prep_bw  <<<(OUT_F * IN_F / 8) / 256, 256, 0, stream>>>(bw, Bt, sum_ptr);
  prep_grid<<<64 * 64,                  256, 0, stream>>>(grid, Bt, sum_ptr);
  prep_A   <<<(BATCH * IN_F / 8) / 256, 256, 0, stream>>>(x, sum_ptr, Abuf);
  gemm_kernel<<<256, 512, 0, stream>>>(Abuf, Bt, out);
}

// Round 5
// 398.190 us; speedup vs baseline: 1.1546x; 1.0460x over previous
//
#include <hip/hip_runtime.h>

#define IN_F   2048
#define OUT_F  2048
#define GDIM   8
#define BATCH  8192
#define KDIM   4096   // concat K = 2*2048
#define GRID_TOTAL_INV (1.0f / 33554432.0f)  // 1/(2048*2048*8)

#define BK     64
#define NKT    (KDIM / BK)   // 64 K-tiles
#define BUFSZ  65536         // per buffer: A 32K (2 kk-regions) + B 32K
#define BOFF   32768         // B offset within buffer
#define REG    16384         // one kk-region: 256 rows x 32 k x 2B

typedef __bf16 bf16x8 __attribute__((ext_vector_type(8)));
typedef float  f32x4  __attribute__((ext_vector_type(4)));
typedef unsigned short u16x8 __attribute__((ext_vector_type(8)));

__device__ __forceinline__ unsigned short f2bf(float f) {
  union { float f; unsigned int u; } v; v.f = f;
  unsigned int r = v.u + 0x7fffu + ((v.u >> 16) & 1u);  // RNE
  return (unsigned short)(r >> 16);
}

__device__ __forceinline__ void gload_lds16(const void* g, void* l) {
  __builtin_amdgcn_global_load_lds(
      (const __attribute__((address_space(1))) void*)g,
      (__attribute__((address_space(3))) void*)l, 16, 0, 0);
}

// ---------------- prep 1: base_weight (OUT,IN) f32 -> Bt[o][k<2048] bf16 ----
__global__ __launch_bounds__(256) void prep_bw(const float* __restrict__ bw,
                                               unsigned short* __restrict__ Bt,
                                               float* __restrict__ sum_ptr) {
  if (blockIdx.x == 0 && threadIdx.x == 0) *sum_ptr = 0.0f;  // zero mean-acc
  size_t i8 = ((size_t)blockIdx.x * 256 + threadIdx.x) * 8;
  const float4* p = reinterpret_cast<const float4*>(bw + i8);
  float4 a = p[0], b = p[1];
  u16x8 v;
  v[0] = f2bf(a.x); v[1] = f2bf(a.y); v[2] = f2bf(a.z); v[3] = f2bf(a.w);
  v[4] = f2bf(b.x); v[5] = f2bf(b.y); v[6] = f2bf(b.z); v[7] = f2bf(b.w);
  size_t o = i8 >> 11;       // row (out)
  size_t k = i8 & 2047;      // col (in)
  *reinterpret_cast<u16x8*>(Bt + o * KDIM + k) = v;
}

// ---------------- prep 2: grid (IN,OUT,8) f32 -> Bt[o][2048+i] = sum_g, + mean
__global__ __launch_bounds__(256) void prep_grid(const float* __restrict__ grid,
                                                 unsigned short* __restrict__ Bt,
                                                 float* __restrict__ sum_ptr) {
  __shared__ float tile[32][33];
  __shared__ float wsum[4];
  int bi = blockIdx.x >> 6;   // i-tile (64 tiles of 32)
  int bo = blockIdx.x & 63;   // o-tile
  int i0 = bi << 5, o0 = bo << 5;
  int t = threadIdx.x;
  float local = 0.f;
#pragma unroll
  for (int p = 0; p < 4; ++p) {
    int li = t + 256 * p;
    int il = li >> 5, ol = li & 31;
    const float4* g4 = reinterpret_cast<const float4*>(
        grid + ((size_t)(i0 + il) * OUT_F + (size_t)(o0 + ol)) * GDIM);
    float4 a = g4[0], b = g4[1];
    float s = ((a.x + a.y) + (a.z + a.w)) + ((b.x + b.y) + (b.z + b.w));
    tile[il][ol] = s;
    local += s;
  }
#pragma unroll
  for (int off = 32; off >= 1; off >>= 1) local += __shfl_down(local, off, 64);
  int lane = t & 63, w = t >> 6;
  if (lane == 0) wsum[w] = local;
  __syncthreads();
#pragma unroll
  for (int p = 0; p < 4; ++p) {
    int li = t + 256 * p;
    int ol = li >> 5, il = li & 31;   // transposed: consecutive t -> consecutive i
    Bt[(size_t)(o0 + ol) * KDIM + IN_F + (i0 + il)] = f2bf(tile[il][ol]);
  }
  if (t == 0) atomicAdd(sum_ptr, (wsum[0] + wsum[1]) + (wsum[2] + wsum[3]));
}

// ---------------- prep 3: A = [bf16(x) | bf16(exp(-(x-m)^2))] ----------------
__global__ __launch_bounds__(256) void prep_A(const float* __restrict__ x,
                                              const float* __restrict__ sum_ptr,
                                              unsigned short* __restrict__ Abuf) {
  float m = *sum_ptr * GRID_TOTAL_INV;
  size_t i8 = ((size_t)blockIdx.x * 256 + threadIdx.x) * 8;
  const float4* p = reinterpret_cast<const float4*>(x + i8);
  float4 a = p[0], b = p[1];
  float xs[8] = {a.x, a.y, a.z, a.w, b.x, b.y, b.z, b.w};
  u16x8 xv, bv;
#pragma unroll
  for (int j = 0; j < 8; ++j) {
    xv[j] = f2bf(xs[j]);
    float d = xs[j] - m;
    bv[j] = f2bf(__expf(-d * d));
  }
  size_t bi = i8 >> 11;
  size_t k  = i8 & 2047;
  *reinterpret_cast<u16x8*>(Abuf + bi * KDIM + k) = xv;
  *reinterpret_cast<u16x8*>(Abuf + bi * KDIM + IN_F + k) = bv;
}

// ---------------- GEMM: C(8192x2048) = A(8192x4096) * Bt(2048x4096)^T --------
// m201-style 4-phase/K-tile schedule (T2+T3+T4+T5). 256x256 tile, BK=64,
// 8 waves (2Mx4N), per-wave 128x64 = acc[8][4], 64 MFMA/K-tile/wave.
// LDS: 2 buffers x {A[kk][256][32], B[kk][256][32]} = 128 KiB. Per phase:
//   p0: stage A(t+1)kk0 | vmcnt(6) barrier | ds_read af0-3/bf kk0 | 16 MFMA
//   p1: ds_read af4-7 kk0 | stage B(t+1)kk0 | 16 MFMA
//   p2: stage A(t+1)kk1 | vmcnt(6) barrier | ds_read af0-3/bf kk1 | 16 MFMA
//   p3: ds_read af4-7 kk1 | stage B(t+1)kk1 | 16 MFMA
// vmcnt never drains to 0 in the main loop (3-4 half-tiles always in flight).
// Write-hazard proof: stage at phase p targets a region whose readers finished
// (lgkm-drained within their phase) at least one crossed barrier before any
// wave can issue the overwriting stage — checked for all 4 phases.
// Swizzle (both-sides, rule 21): 16B-chunk c stored at c ^ ((row>>2)&3) via
// pre-swizzled global source; ds_read applies the same XOR.
__global__ __launch_bounds__(512, 2) void gemm_kernel(
    const unsigned short* __restrict__ A,
    const unsigned short* __restrict__ B,
    float* __restrict__ C) {
  __shared__ __align__(16) char lds[2 * BUFSZ];  // 128 KiB
  const int t    = threadIdx.x;
  const int lane = t & 63;
  const int wid  = t >> 6;        // 0..7
  const int wm   = wid >> 2;      // 0..1
  const int wn   = wid & 3;       // 0..3
  // XCD-clustered mapping: xcd = bx&7 gets bm in [xcd*4, xcd*4+4) x all 8 bn.
  const int bx = blockIdx.x;
  const int bm = ((bx & 7) << 2) | ((bx >> 3) & 3);  // 0..31
  const int bn = bx >> 5;                            // 0..7

  f32x4 acc[8][4] = {};
  bf16x8 af[4], bf[4];

  // staging: thread t covers region rows (t>>2) and 128+(t>>2), chunk (t&3).
  // source chunk pre-swizzled: cs = (t&3) ^ ((row>>2)&3) = (t&3) ^ ((t>>4)&3).
  const int cs = (t & 3) ^ ((t >> 4) & 3);
  const unsigned short* aStage = A + ((size_t)(bm * 256 + (t >> 2)) * KDIM) + cs * 8;
  const unsigned short* bStage = B + ((size_t)(bn * 256 + (t >> 2)) * KDIM) + cs * 8;
  const int dOff = t * 16;

  // ds_read: global chunk (lane>>4) lives at LDS chunk (lane>>4)^((row>>2)&3);
  // (row>>2)&3 == (lane>>2)&3 for all frag rows (row = 16-aligned + (lane&15)).
  const int sc  = (lane >> 4) ^ ((lane >> 2) & 3);
  const int aRd = (wm * 128 + (lane & 15)) * 64 + sc * 16;
  const int bRd = (wn * 64  + (lane & 15)) * 64 + sc * 16;

#define STAGE_R(wb, kt, opOff, kk, src)                                        \
  gload_lds16((src) + (size_t)(kt) * BK + (kk) * 32,                           \
              (wb) + (opOff) + (kk) * REG + dOff);                             \
  gload_lds16((src) + 128 * KDIM + (size_t)(kt) * BK + (kk) * 32,              \
              (wb) + (opOff) + (kk) * REG + 8192 + dOff);

#define DSREAD_A(rb, kk, mb)                                                   \
  _Pragma("unroll")                                                            \
  for (int i_ = 0; i_ < 4; ++i_)                                               \
    af[i_] = *reinterpret_cast<const bf16x8*>(                                 \
        (rb) + (kk) * REG + aRd + ((mb) + i_) * 1024);

#define DSREAD_B(rb, kk)                                                       \
  _Pragma("unroll")                                                            \
  for (int n_ = 0; n_ < 4; ++n_)                                               \
    bf[n_] = *reinterpret_cast<const bf16x8*>(                                 \
        (rb) + BOFF + (kk) * REG + bRd + n_ * 1024);

#define LGKM0                                                                  \
  asm volatile("s_waitcnt lgkmcnt(0)" ::: "memory");                           \
  __builtin_amdgcn_sched_barrier(0);

#define MFMAQ(mb)                                                              \
  __builtin_amdgcn_s_setprio(1);                                               \
  _Pragma("unroll")                                                            \
  for (int i_ = 0; i_ < 4; ++i_)                                               \
    _Pragma("unroll")                                                          \
    for (int n_ = 0; n_ < 4; ++n_)                                             \
      acc[(mb) + i_][n_] = __builtin_amdgcn_mfma_f32_16x16x32_bf16(            \
          af[i_], bf[n_], acc[(mb) + i_][n_], 0, 0, 0);                        \
  __builtin_amdgcn_s_setprio(0);

#define VMCNT(n) asm volatile("s_waitcnt vmcnt(" #n ")" ::: "memory");

  // prologue: tile 0, regions in stream order A-kk0, B-kk0, A-kk1, B-kk1
  STAGE_R(lds, 0, 0,    0, aStage);
  STAGE_R(lds, 0, BOFF, 0, bStage);
  STAGE_R(lds, 0, 0,    1, aStage);
  STAGE_R(lds, 0, BOFF, 1, bStage);

  for (int kt = 0; kt < NKT - 1; ++kt) {
    const char* rb = lds + (kt & 1) * BUFSZ;
    char* wb = lds + ((kt + 1) & 1) * BUFSZ;
    // p0
    STAGE_R(wb, kt + 1, 0, 0, aStage);
    VMCNT(6);
    __builtin_amdgcn_s_barrier();
    DSREAD_A(rb, 0, 0); DSREAD_B(rb, 0);
    LGKM0; MFMAQ(0);
    // p1
    DSREAD_A(rb, 0, 4);
    STAGE_R(wb, kt + 1, BOFF, 0, bStage);
    LGKM0; MFMAQ(4);
    // p2
    STAGE_R(wb, kt + 1, 0, 1, aStage);
    VMCNT(6);
    __builtin_amdgcn_s_barrier();
    DSREAD_A(rb, 1, 0); DSREAD_B(rb, 1);
    LGKM0; MFMAQ(0);
    // p3
    DSREAD_A(rb, 1, 4);
    STAGE_R(wb, kt + 1, BOFF, 1, bStage);
    LGKM0; MFMAQ(4);
  }
  {  // tail tile NKT-1 (odd -> buffer 1), no staging; drain 4 then 0
    const char* rb = lds + ((NKT - 1) & 1) * BUFSZ;
    VMCNT(4);
    __builtin_amdgcn_s_barrier();
    DSREAD_A(rb, 0, 0); DSREAD_B(rb, 0); LGKM0; MFMAQ(0);
    DSREAD_A(rb, 0, 4);                  LGKM0; MFMAQ(4);
    VMCNT(0);
    __builtin_amdgcn_s_barrier();
    DSREAD_A(rb, 1, 0); DSREAD_B(rb, 1); LGKM0; MFMAQ(0);
    DSREAD_A(rb, 1, 4);                  LGKM0; MFMAQ(4);
  }

  // epilogue: C/D layout col=lane&15, row=(lane>>4)*4+reg  [m89/m91 verified]
  const int rg = lane >> 4, cc = lane & 15;
  const size_t crow0 = (size_t)bm * 256 + wm * 128;
  const size_t ccol0 = (size_t)bn * 256 + wn * 64;
#pragma unroll
  for (int m = 0; m < 8; ++m)
#pragma unroll
    for (int n = 0; n < 4; ++n)
#pragma unroll
      for (int rr = 0; rr < 4; ++rr) {
        size_t row = crow0 + (size_t)m * 16 + rg * 4 + rr;
        size_t col = ccol0 + (size_t)n * 16 + cc;
        C[row * OUT_F + col] = acc[m][n][rr];
      }
}

extern "C" void kernel_launch(void* const* d_in, const int* in_sizes, int n_in,
                              void* d_out, int out_size, void* d_ws, size_t ws_size,
                              hipStream_t stream) {
  const float* x    = (const float*)d_in[0];
  const float* bw   = (const float*)d_in[1];
  const float* grid = (const float*)d_in[2];
  float* out = (float*)d_out;

  // workspace: A (8192x4096 bf16, 64MB) | Bt (2048x4096 bf16, 16MB) | sum (4B)
  unsigned short* Abuf = (unsigned short*)d_ws;
  unsigned short* Bt   = Abuf + (size_t)BATCH * KDIM;
  float* sum_ptr = (float*)(Bt + (size_t)OUT_F * KDIM);

  prep_bw  <<<(OUT_F * IN_F / 8) / 256, 256, 0, stream>>>(bw, Bt, sum_ptr);
  prep_grid<<<64 * 64,                  256, 0, stream>>>(grid, Bt, sum_ptr);
  prep_A   <<<(BATCH * IN_F / 8) / 256, 256, 0, stream>>>(x, sum_ptr, Abuf);
  gemm_kernel<<<256, 512, 0, stream>>>(Abuf, Bt, out);
}